// Round 13
// baseline (369.814 us; speedup 1.0000x reference)
//
#include <hip/hip_runtime.h>

// SGC-Res: out = LayerNorm( (A @ feat) @ W^T + b )
// Identity: (A @ F) @ W^T = A @ (F @ W^T) = A @ G  (G in bf16).
// R13: k_node2 reverted to the proven 8-deep form (R12's 16-deep regressed
// 62->85us).  k_scatgemm moves to 1024-thread blocks: the scatter tail was
// 12.5% occupancy (4 waves/CU); 16 waves/CU gives 4x store parallelism at
// unchanged fragmentation.  Gemm path drops LDS (uniform float4 reads of
// feat rows hit L1), handling 256 rows/block.
// Pipeline:
//   k_bhist:    per-block LDS histogram over row-buckets (64 rows/bkt)
//   k_bscan:    per-bucket exclusive scan of hist2d column across blocks
//   k_scanb2:   exclusive scan of bucket totals -> bbase[]
//   k_scatgemm: blocks [0,NBLK): bucket-ordered scatter -> epair1 (1024 thr)
//               blocks [NBLK,..): G(bf16) = F @ W^T (256 rows/block, no LDS)
//   k_node2:    one block per bucket: LDS-sort by local row, per-wave
//               register-accumulate (8-deep) + fused bias + LN + store.

typedef unsigned int u32;
typedef unsigned short u16;
typedef unsigned long long u64;
#define RFL(x) __builtin_amdgcn_readfirstlane(x)

#define NBLKC 256   // scatter blocks
#define MAXBK 2048  // bucket count capacity in LDS (N <= 131072)
#define CAP 2048    // per-bucket edge capacity in k_node2 LDS

__device__ __forceinline__ float bf2f(u16 v) {
    return __uint_as_float((u32)v << 16);
}
__device__ __forceinline__ u16 f2bf(float f) {
    u32 b = __float_as_uint(f);
    return (u16)((b + 0x7FFFu + ((b >> 16) & 1u)) >> 16);  // RNE
}

__global__ __launch_bounds__(256) void k_bhist(const int* __restrict__ row,
                                               u32* __restrict__ hist2d,
                                               int E, int NBK, int CH) {
    __shared__ u32 cnt[MAXBK];
    int tid = threadIdx.x;
    for (int i = tid; i < NBK; i += 256) cnt[i] = 0;
    __syncthreads();
    int e0 = blockIdx.x * CH;                 // CH mult of 4
    int e1 = e0 + CH; if (e1 > E) e1 = E;
    int ev = e1 & ~3;
    for (int i = e0 + tid * 4; i < ev; i += 1024) {
        int4 r = *reinterpret_cast<const int4*>(&row[i]);
        atomicAdd(&cnt[(u32)r.x >> 6], 1u);
        atomicAdd(&cnt[(u32)r.y >> 6], 1u);
        atomicAdd(&cnt[(u32)r.z >> 6], 1u);
        atomicAdd(&cnt[(u32)r.w >> 6], 1u);
    }
    { int i = ev + tid; if (i < e1) atomicAdd(&cnt[(u32)row[i] >> 6], 1u); }
    __syncthreads();
    u32* dst = hist2d + (size_t)blockIdx.x * NBK;
    for (int i = tid; i < NBK; i += 256) dst[i] = cnt[i];
}

__device__ __forceinline__ u32 blk_scan256(u32 v, u32* wsum, u32& total) {
    int lane = threadIdx.x & 63, wid = threadIdx.x >> 6;
    u32 incl = v;
#pragma unroll
    for (int o = 1; o < 64; o <<= 1) {
        u32 u = __shfl_up(incl, o);
        if (lane >= o) incl += u;
    }
    if (lane == 63) wsum[wid] = incl;
    __syncthreads();
    u32 woff = 0;
    for (int w = 0; w < wid; ++w) woff += wsum[w];
    total = wsum[0] + wsum[1] + wsum[2] + wsum[3];
    __syncthreads();
    return woff + incl - v;  // exclusive prefix
}

__global__ __launch_bounds__(256) void k_bscan(u32* __restrict__ hist2d,
                                               u32* __restrict__ btot,
                                               int NBLK, int NBK) {
    __shared__ u32 wsum[4];
    int bkt = blockIdx.x;
    u32 carry = 0;
    for (int r = 0; r < NBLK; r += 256) {
        int blk = r + threadIdx.x;
        u32 v = (blk < NBLK) ? hist2d[(size_t)blk * NBK + bkt] : 0;
        u32 tot;
        u32 ex = blk_scan256(v, wsum, tot);
        if (blk < NBLK) hist2d[(size_t)blk * NBK + bkt] = ex + carry;
        carry += tot;
    }
    if (threadIdx.x == 0) btot[bkt] = carry;
}

__global__ __launch_bounds__(256) void k_scanb2(const u32* __restrict__ btot,
                                                u32* __restrict__ bbase,
                                                int NBK, int E) {
    __shared__ u32 wsum[4];
    u32 carry = 0;
    for (int r = 0; r < NBK; r += 256) {
        int i = r + threadIdx.x;
        u32 v = (i < NBK) ? btot[i] : 0;
        u32 tot;
        u32 ex = blk_scan256(v, wsum, tot);
        if (i < NBK) bbase[i] = ex + carry;
        carry += tot;
    }
    if (threadIdx.x == 0) bbase[NBK] = (u32)E;
}

// Fused, 1024-thr blocks: [0,NBLK) scatter; [NBLK,..) gemm (256 rows each).
__global__ __launch_bounds__(1024, 1) void k_scatgemm(
    const int* __restrict__ row, const int* __restrict__ col,
    const float* __restrict__ vals, const u32* __restrict__ hist2d,
    const u32* __restrict__ bbase, u64* __restrict__ epair1,
    const float* __restrict__ feat, const float* __restrict__ W,
    u16* __restrict__ G, int E, int N, int NBK, int NBLK, int CH)
{
    __shared__ u32 smem[2 * MAXBK];  // 16 KB (scatter only)
    int tid = threadIdx.x;
    if ((int)blockIdx.x < NBLK) {
        // ---------------- scatter path (16 waves) ----------------
        u32* lbase = smem;         // NBK
        u32* lcnt  = smem + NBK;   // NBK
        int blk = blockIdx.x;
        const u32* hrow = hist2d + (size_t)blk * NBK;
        for (int i = tid; i < NBK; i += 1024) {
            lbase[i] = bbase[i] + hrow[i];
            lcnt[i] = 0;
        }
        __syncthreads();
        int e0 = blk * CH;
        int e1 = e0 + CH; if (e1 > E) e1 = E;
        int ev = e1 & ~3;
        for (int i = e0 + tid * 4; i < ev; i += 4096) {
            int4 r = *reinterpret_cast<const int4*>(&row[i]);
            int4 c = *reinterpret_cast<const int4*>(&col[i]);
            float4 v = *reinterpret_cast<const float4*>(&vals[i]);
            u32 k0 = (u32)r.x >> 6, k1 = (u32)r.y >> 6;
            u32 k2 = (u32)r.z >> 6, k3 = (u32)r.w >> 6;
            u32 q0 = atomicAdd(&lcnt[k0], 1u);
            u32 q1 = atomicAdd(&lcnt[k1], 1u);
            u32 q2 = atomicAdd(&lcnt[k2], 1u);
            u32 q3 = atomicAdd(&lcnt[k3], 1u);
            epair1[lbase[k0] + q0] = (u64)((u32)c.x | (((u32)r.x & 63u) << 26))
                                   | ((u64)__float_as_uint(v.x) << 32);
            epair1[lbase[k1] + q1] = (u64)((u32)c.y | (((u32)r.y & 63u) << 26))
                                   | ((u64)__float_as_uint(v.y) << 32);
            epair1[lbase[k2] + q2] = (u64)((u32)c.z | (((u32)r.z & 63u) << 26))
                                   | ((u64)__float_as_uint(v.z) << 32);
            epair1[lbase[k3] + q3] = (u64)((u32)c.w | (((u32)r.w & 63u) << 26))
                                   | ((u64)__float_as_uint(v.w) << 32);
        }
        {
            int i = ev + tid;
            if (i < e1) {
                u32 r = (u32)row[i];
                u32 k = r >> 6;
                u32 q = atomicAdd(&lcnt[k], 1u);
                epair1[lbase[k] + q] = (u64)((u32)col[i] | ((r & 63u) << 26))
                                     | ((u64)__float_as_uint(vals[i]) << 32);
            }
        }
    } else {
        // -------- gemm path: G(bf16) = F @ W^T, no LDS, 256 rows --------
        int lane = tid & 63, wid = tid >> 6;   // wid 0..15
        int n0 = ((int)blockIdx.x - NBLK) * 256 + wid * 16;
        float wr[64];
#pragma unroll
        for (int d4 = 0; d4 < 16; ++d4) {
            float4 w4 = *reinterpret_cast<const float4*>(&W[lane * 64 + d4 * 4]);
            wr[d4 * 4 + 0] = w4.x; wr[d4 * 4 + 1] = w4.y;
            wr[d4 * 4 + 2] = w4.z; wr[d4 * 4 + 3] = w4.w;
        }
        for (int j = 0; j < 16; ++j) {
            int r = n0 + j;
            if (r >= N) break;
            const float4* fr = reinterpret_cast<const float4*>(&feat[(size_t)r * 64]);
            float oa[4] = {0.f, 0.f, 0.f, 0.f};
#pragma unroll
            for (int d4 = 0; d4 < 16; ++d4) {
                float4 h4 = fr[d4];   // uniform address -> broadcast, L1-hot
                oa[d4 & 3] = fmaf(h4.x, wr[d4 * 4 + 0],
                            fmaf(h4.y, wr[d4 * 4 + 1],
                            fmaf(h4.z, wr[d4 * 4 + 2],
                            fmaf(h4.w, wr[d4 * 4 + 3], oa[d4 & 3]))));
            }
            G[(size_t)r * 64 + lane] = f2bf((oa[0] + oa[1]) + (oa[2] + oa[3]));
        }
    }
}

// One block per bucket: LDS-sort edges by local row, then per-wave rows with
// 8-deep register accumulation + fused LayerNorm.  lane = class c. (R8-proven.)
__global__ __launch_bounds__(256) void k_node2(
    const u16* __restrict__ G, const u64* __restrict__ epair1,
    const u32* __restrict__ bbase, const float* __restrict__ bias,
    const float* __restrict__ gamma, const float* __restrict__ beta,
    float* __restrict__ out, int N)
{
    __shared__ u64 sp[CAP];
    __shared__ u32 cnt[64], base[64], cnt2[64];
    int tid = threadIdx.x, lane = tid & 63, wid = tid >> 6;
    int bkt = blockIdx.x;
    if (tid < 64) { cnt[tid] = 0; cnt2[tid] = 0; }
    __syncthreads();
    int s = RFL((int)bbase[bkt]);
    int t = RFL((int)bbase[bkt + 1]);
    int m = t - s;
    bool fits = (m <= CAP);

    const u32* meta1 = (const u32*)epair1;
    for (int i = s + tid; i < t; i += 256)
        atomicAdd(&cnt[meta1[2 * (size_t)i] >> 26], 1u);
    __syncthreads();
    if (tid < 64) {
        u32 v = cnt[tid];
        u32 incl = v;
#pragma unroll
        for (int o = 1; o < 64; o <<= 1) {
            u32 u = __shfl_up(incl, o);
            if (tid >= o) incl += u;
        }
        base[tid] = incl - v;
    }
    __syncthreads();
    if (fits) {
        for (int i = s + tid; i < t; i += 256) {
            u64 p = epair1[i];
            u32 mm = (u32)p;
            u32 r = mm >> 26;
            u32 rank = atomicAdd(&cnt2[r], 1u);
            sp[base[r] + rank] = (p & 0xFFFFFFFF00000000ull) | (u64)(mm & 0x03FFFFFFu);
        }
    }
    __syncthreads();

    int rbase = bkt << 6;
    for (int j = 0; j < 16; ++j) {
        int r = wid * 16 + j;
        int n = rbase + r;
        if (n >= N) break;
        float acc0 = 0.f, acc1 = 0.f;
        if (fits) {
            int e0 = base[r], e1 = base[r] + cnt[r];
            int i = e0;
            for (; i + 8 <= e1; i += 8) {
                u64 p0 = sp[i],     p1 = sp[i + 1];
                u64 p2 = sp[i + 2], p3 = sp[i + 3];
                u64 p4 = sp[i + 4], p5 = sp[i + 5];
                u64 p6 = sp[i + 6], p7 = sp[i + 7];
                u32 c0 = RFL((u32)p0), b0 = RFL((u32)(p0 >> 32));
                u32 c1 = RFL((u32)p1), b1 = RFL((u32)(p1 >> 32));
                u32 c2 = RFL((u32)p2), b2 = RFL((u32)(p2 >> 32));
                u32 c3 = RFL((u32)p3), b3 = RFL((u32)(p3 >> 32));
                u32 c4 = RFL((u32)p4), b4 = RFL((u32)(p4 >> 32));
                u32 c5 = RFL((u32)p5), b5 = RFL((u32)(p5 >> 32));
                u32 c6 = RFL((u32)p6), b6 = RFL((u32)(p6 >> 32));
                u32 c7 = RFL((u32)p7), b7 = RFL((u32)(p7 >> 32));
                float g0 = bf2f(G[((size_t)c0 << 6) | lane]);
                float g1 = bf2f(G[((size_t)c1 << 6) | lane]);
                float g2 = bf2f(G[((size_t)c2 << 6) | lane]);
                float g3 = bf2f(G[((size_t)c3 << 6) | lane]);
                float g4 = bf2f(G[((size_t)c4 << 6) | lane]);
                float g5 = bf2f(G[((size_t)c5 << 6) | lane]);
                float g6 = bf2f(G[((size_t)c6 << 6) | lane]);
                float g7 = bf2f(G[((size_t)c7 << 6) | lane]);
                acc0 = fmaf(__uint_as_float(b0), g0, acc0);
                acc1 = fmaf(__uint_as_float(b1), g1, acc1);
                acc0 = fmaf(__uint_as_float(b2), g2, acc0);
                acc1 = fmaf(__uint_as_float(b3), g3, acc1);
                acc0 = fmaf(__uint_as_float(b4), g4, acc0);
                acc1 = fmaf(__uint_as_float(b5), g5, acc1);
                acc0 = fmaf(__uint_as_float(b6), g6, acc0);
                acc1 = fmaf(__uint_as_float(b7), g7, acc1);
            }
            for (; i < e1; ++i) {
                u64 p = sp[i];
                u32 c = RFL((u32)p), b = RFL((u32)(p >> 32));
                acc0 = fmaf(__uint_as_float(b), bf2f(G[((size_t)c << 6) | lane]), acc0);
            }
        } else {
            for (int i = s; i < t; ++i) {
                u64 p = epair1[i];
                u32 mm = RFL((u32)p);
                if ((int)(mm >> 26) == r) {
                    u32 b = RFL((u32)(p >> 32));
                    acc0 = fmaf(__uint_as_float(b),
                                bf2f(G[((size_t)(mm & 0x03FFFFFFu) << 6) | lane]), acc0);
                }
            }
        }
        float o = acc0 + acc1 + bias[lane];

        float ssum = o;
#pragma unroll
        for (int off = 32; off; off >>= 1) ssum += __shfl_xor(ssum, off);
        float mu = ssum * 0.015625f;
        float dv = o - mu;
        float vs = dv * dv;
#pragma unroll
        for (int off = 32; off; off >>= 1) vs += __shfl_xor(vs, off);
        float inv = rsqrtf(vs * 0.015625f + 1e-5f);
        out[((size_t)n << 6) + lane] = dv * inv * gamma[lane] + beta[lane];
    }
}

extern "C" void kernel_launch(void* const* d_in, const int* in_sizes, int n_in,
                              void* d_out, int out_size, void* d_ws, size_t ws_size,
                              hipStream_t stream) {
    const float* feat  = (const float*)d_in[0];
    // d_in[1] = feat_ori: dead code in reference, unused
    const int*   row   = (const int*)d_in[2];
    const int*   col   = (const int*)d_in[3];
    const float* vals  = (const float*)d_in[4];
    const float* W     = (const float*)d_in[5];
    const float* bias  = (const float*)d_in[6];
    const float* gamma = (const float*)d_in[7];
    const float* beta  = (const float*)d_in[8];
    float* out = (float*)d_out;

    const int D = 64;
    int N = in_sizes[0] / D;   // 100000 -> NBK = 1563 <= MAXBK
    int E = in_sizes[2];

    int NBK  = (N + 63) / 64;
    int NBLK = NBLKC;
    int CH   = (((E + NBLK - 1) / NBLK) + 3) & ~3;   // edges/block, mult of 4
    int NG   = (N + 255) / 256;                      // gemm blocks (256 rows)

    // ws layout: G (bf16) | epair1 | hist2d (1.6MB) | btot | bbase
    char* ws = (char*)d_ws;
    u16*   G      = (u16*)ws;
    size_t off1   = (((size_t)N * 128) + 255) & ~(size_t)255;
    u64*   epair1 = (u64*)(ws + off1);
    size_t off2   = off1 + (((size_t)E * 8 + 255) & ~(size_t)255);
    u32*   hist2d = (u32*)(ws + off2);
    size_t off3   = off2 + (((size_t)NBLK * NBK * 4 + 255) & ~(size_t)255);
    u32*   btot   = (u32*)(ws + off3);
    u32*   bbase  = btot + NBK;          // NBK+1 entries

    k_bhist   <<<NBLK, 256, 0, stream>>>(row, hist2d, E, NBK, CH);
    k_bscan   <<<NBK, 256, 0, stream>>>(hist2d, btot, NBLK, NBK);
    k_scanb2  <<<1, 256, 0, stream>>>(btot, bbase, NBK, E);
    k_scatgemm<<<NBLK + NG, 1024, 0, stream>>>(row, col, vals, hist2d, bbase,
                                               epair1, feat, W, G,
                                               E, N, NBK, NBLK, CH);
    k_node2   <<<NBK, 256, 0, stream>>>(G, epair1, bbase, bias, gamma, beta,
                                        out, N);
}

// Round 14
// 134.245 us; speedup vs baseline: 2.7548x; 2.7548x over previous
//
#include <hip/hip_runtime.h>

// SGC-Res: out = LayerNorm( (A @ feat) @ W^T + b )
// Identity: (A @ F) @ W^T = A @ (F @ W^T) = A @ G  (G in bf16).
// R14 = R9's proven aux (best total: 130us) + ONE change: k_node2 runs
// 2 blocks per bucket (32 rows each).  R9's node2 was grid-limited
// (6.1 blocks/CU, 53% occupancy); 3126 blocks + 11KB LDS reaches the
// 32-waves/CU cap.  (R13 lesson: 1024-thr fusion spilled wr[64] - reverted.)
// Pipeline:
//   k_bhist:    per-block LDS histogram over row-buckets (64 rows/bkt)
//   k_bscan:    per-bucket exclusive scan of hist2d column across blocks
//   k_scanb2:   exclusive scan of bucket totals -> bbase[]
//   k_scatgemm: blocks [0,64): bucket-ordered scatter -> epair1
//               blocks [64,..): G(bf16) = F @ W^T
//   k_node2:    2 blocks/bucket: LDS-sort own 32 rows, 8-deep register
//               gather-accumulate + fused bias + LayerNorm + store.

typedef unsigned int u32;
typedef unsigned short u16;
typedef unsigned long long u64;
#define RFL(x) __builtin_amdgcn_readfirstlane(x)

#define NBLKC 64    // binning blocks (R9-proven)
#define MAXBK 2048  // bucket count capacity in LDS (N <= 131072)
#define CAP 1280    // per-half-bucket edge capacity in k_node2 LDS

__device__ __forceinline__ float bf2f(u16 v) {
    return __uint_as_float((u32)v << 16);
}
__device__ __forceinline__ u16 f2bf(float f) {
    u32 b = __float_as_uint(f);
    return (u16)((b + 0x7FFFu + ((b >> 16) & 1u)) >> 16);  // RNE
}

__global__ __launch_bounds__(256) void k_bhist(const int* __restrict__ row,
                                               u32* __restrict__ hist2d,
                                               int E, int NBK, int CH) {
    __shared__ u32 cnt[MAXBK];
    int tid = threadIdx.x;
    for (int i = tid; i < NBK; i += 256) cnt[i] = 0;
    __syncthreads();
    int e0 = blockIdx.x * CH;                 // CH mult of 4
    int e1 = e0 + CH; if (e1 > E) e1 = E;
    int ev = e1 & ~3;
    for (int i = e0 + tid * 4; i < ev; i += 1024) {
        int4 r = *reinterpret_cast<const int4*>(&row[i]);
        atomicAdd(&cnt[(u32)r.x >> 6], 1u);
        atomicAdd(&cnt[(u32)r.y >> 6], 1u);
        atomicAdd(&cnt[(u32)r.z >> 6], 1u);
        atomicAdd(&cnt[(u32)r.w >> 6], 1u);
    }
    { int i = ev + tid; if (i < e1) atomicAdd(&cnt[(u32)row[i] >> 6], 1u); }
    __syncthreads();
    u32* dst = hist2d + (size_t)blockIdx.x * NBK;
    for (int i = tid; i < NBK; i += 256) dst[i] = cnt[i];
}

__device__ __forceinline__ u32 blk_scan256(u32 v, u32* wsum, u32& total) {
    int lane = threadIdx.x & 63, wid = threadIdx.x >> 6;
    u32 incl = v;
#pragma unroll
    for (int o = 1; o < 64; o <<= 1) {
        u32 u = __shfl_up(incl, o);
        if (lane >= o) incl += u;
    }
    if (lane == 63) wsum[wid] = incl;
    __syncthreads();
    u32 woff = 0;
    for (int w = 0; w < wid; ++w) woff += wsum[w];
    total = wsum[0] + wsum[1] + wsum[2] + wsum[3];
    __syncthreads();
    return woff + incl - v;  // exclusive prefix
}

__global__ __launch_bounds__(256) void k_bscan(u32* __restrict__ hist2d,
                                               u32* __restrict__ btot,
                                               int NBLK, int NBK) {
    __shared__ u32 wsum[4];
    int bkt = blockIdx.x;
    u32 carry = 0;
    for (int r = 0; r < NBLK; r += 256) {
        int blk = r + threadIdx.x;
        u32 v = (blk < NBLK) ? hist2d[(size_t)blk * NBK + bkt] : 0;
        u32 tot;
        u32 ex = blk_scan256(v, wsum, tot);
        if (blk < NBLK) hist2d[(size_t)blk * NBK + bkt] = ex + carry;
        carry += tot;
    }
    if (threadIdx.x == 0) btot[bkt] = carry;
}

__global__ __launch_bounds__(256) void k_scanb2(const u32* __restrict__ btot,
                                                u32* __restrict__ bbase,
                                                int NBK, int E) {
    __shared__ u32 wsum[4];
    u32 carry = 0;
    for (int r = 0; r < NBK; r += 256) {
        int i = r + threadIdx.x;
        u32 v = (i < NBK) ? btot[i] : 0;
        u32 tot;
        u32 ex = blk_scan256(v, wsum, tot);
        if (i < NBK) bbase[i] = ex + carry;
        carry += tot;
    }
    if (threadIdx.x == 0) bbase[NBK] = (u32)E;
}

// Fused: blocks [0,NBLK) scatter edges; blocks [NBLK, NBLK+NG) compute G.
__global__ __launch_bounds__(256) void k_scatgemm(
    const int* __restrict__ row, const int* __restrict__ col,
    const float* __restrict__ vals, const u32* __restrict__ hist2d,
    const u32* __restrict__ bbase, u64* __restrict__ epair1,
    const float* __restrict__ feat, const float* __restrict__ W,
    u16* __restrict__ G, int E, int N, int NBK, int NBLK, int CH)
{
    __shared__ __align__(16) u32 smem[4096];  // 16 KB union
    int tid = threadIdx.x;
    if ((int)blockIdx.x < NBLK) {
        // ---------------- scatter path ----------------
        u32* lbase = smem;         // NBK
        u32* lcnt  = smem + NBK;   // NBK
        int blk = blockIdx.x;
        const u32* hrow = hist2d + (size_t)blk * NBK;
        for (int i = tid; i < NBK; i += 256) {
            lbase[i] = bbase[i] + hrow[i];
            lcnt[i] = 0;
        }
        __syncthreads();
        int e0 = blk * CH;
        int e1 = e0 + CH; if (e1 > E) e1 = E;
        int ev = e1 & ~3;
        for (int i = e0 + tid * 4; i < ev; i += 1024) {
            int4 r = *reinterpret_cast<const int4*>(&row[i]);
            int4 c = *reinterpret_cast<const int4*>(&col[i]);
            float4 v = *reinterpret_cast<const float4*>(&vals[i]);
            u32 k0 = (u32)r.x >> 6, k1 = (u32)r.y >> 6;
            u32 k2 = (u32)r.z >> 6, k3 = (u32)r.w >> 6;
            u32 q0 = atomicAdd(&lcnt[k0], 1u);
            u32 q1 = atomicAdd(&lcnt[k1], 1u);
            u32 q2 = atomicAdd(&lcnt[k2], 1u);
            u32 q3 = atomicAdd(&lcnt[k3], 1u);
            epair1[lbase[k0] + q0] = (u64)((u32)c.x | (((u32)r.x & 63u) << 26))
                                   | ((u64)__float_as_uint(v.x) << 32);
            epair1[lbase[k1] + q1] = (u64)((u32)c.y | (((u32)r.y & 63u) << 26))
                                   | ((u64)__float_as_uint(v.y) << 32);
            epair1[lbase[k2] + q2] = (u64)((u32)c.z | (((u32)r.z & 63u) << 26))
                                   | ((u64)__float_as_uint(v.z) << 32);
            epair1[lbase[k3] + q3] = (u64)((u32)c.w | (((u32)r.w & 63u) << 26))
                                   | ((u64)__float_as_uint(v.w) << 32);
        }
        {
            int i = ev + tid;
            if (i < e1) {
                u32 r = (u32)row[i];
                u32 k = r >> 6;
                u32 q = atomicAdd(&lcnt[k], 1u);
                epair1[lbase[k] + q] = (u64)((u32)col[i] | ((r & 63u) << 26))
                                     | ((u64)__float_as_uint(vals[i]) << 32);
            }
        }
    } else {
        // ---------------- gemm path: G(bf16) = F @ W^T ----------------
        float* fs = (float*)smem;   // 4096 floats
        int lane = tid & 63, wid = tid >> 6;
        int n0 = ((int)blockIdx.x - NBLK) * 64;
        int valid = N - n0; if (valid > 64) valid = 64;
        int elems = valid * 64;
        for (int idx = tid * 4; idx < elems; idx += 1024)
            *reinterpret_cast<float4*>(&fs[idx]) =
                *reinterpret_cast<const float4*>(&feat[(size_t)n0 * 64 + idx]);
        float wr[64];
#pragma unroll
        for (int d4 = 0; d4 < 16; ++d4) {
            float4 w4 = *reinterpret_cast<const float4*>(&W[lane * 64 + d4 * 4]);
            wr[d4 * 4 + 0] = w4.x; wr[d4 * 4 + 1] = w4.y;
            wr[d4 * 4 + 2] = w4.z; wr[d4 * 4 + 3] = w4.w;
        }
        __syncthreads();
        for (int j = 0; j < 16; ++j) {
            int r = wid * 16 + j;
            if (r >= valid) break;
            float oa[4] = {0.f, 0.f, 0.f, 0.f};
#pragma unroll
            for (int d4 = 0; d4 < 16; ++d4) {
                float4 h4 = *reinterpret_cast<const float4*>(&fs[r * 64 + d4 * 4]);
                oa[d4 & 3] = fmaf(h4.x, wr[d4 * 4 + 0],
                            fmaf(h4.y, wr[d4 * 4 + 1],
                            fmaf(h4.z, wr[d4 * 4 + 2],
                            fmaf(h4.w, wr[d4 * 4 + 3], oa[d4 & 3]))));
            }
            G[(size_t)(n0 + r) * 64 + lane] = f2bf((oa[0] + oa[1]) + (oa[2] + oa[3]));
        }
    }
}

// 2 blocks per bucket: each block owns 32 of the 64 local rows.  Reads the
// whole bucket's epair, LDS-sorts only its rows, then per-wave 8-deep
// register gather-accumulate + fused bias + LayerNorm.  lane = class c.
__global__ __launch_bounds__(256) void k_node2(
    const u16* __restrict__ G, const u64* __restrict__ epair1,
    const u32* __restrict__ bbase, const float* __restrict__ bias,
    const float* __restrict__ gamma, const float* __restrict__ beta,
    float* __restrict__ out, int N)
{
    __shared__ u64 sp[CAP];               // 10 KB
    __shared__ u32 cnt[64], base[64], cnt2[32];
    int tid = threadIdx.x, lane = tid & 63, wid = tid >> 6;
    int bkt  = blockIdx.x >> 1;
    int half = blockIdx.x & 1;
    if (tid < 64) cnt[tid] = 0;
    if (tid < 32) cnt2[tid] = 0;
    __syncthreads();
    int s = RFL((int)bbase[bkt]);
    int t = RFL((int)bbase[bkt + 1]);

    // pass 1: count all 64 local rows (low word only)
    const u32* meta1 = (const u32*)epair1;
    for (int i = s + tid; i < t; i += 256)
        atomicAdd(&cnt[meta1[2 * (size_t)i] >> 26], 1u);
    __syncthreads();
    if (tid < 64) {
        u32 v = cnt[tid];
        u32 incl = v;
#pragma unroll
        for (int o = 1; o < 64; o <<= 1) {
            u32 u = __shfl_up(incl, o);
            if (tid >= o) incl += u;
        }
        base[tid] = incl - v;
    }
    __syncthreads();
    int r0 = half << 5;                   // my rows: [r0, r0+32)
    int myoff = base[r0];
    int myend = (half ? (t - s) : base[32]);
    int myedges = myend - myoff;
    bool fits = (myedges <= CAP);

    // pass 2: rank-scatter MY half's pairs into row-sorted LDS slots
    if (fits) {
        for (int i = s + tid; i < t; i += 256) {
            u64 p = epair1[i];
            u32 mm = (u32)p;
            u32 r = mm >> 26;
            if ((int)(r >> 5) == half) {
                u32 rank = atomicAdd(&cnt2[r & 31u], 1u);
                sp[base[r] - myoff + rank] =
                    (p & 0xFFFFFFFF00000000ull) | (u64)(mm & 0x03FFFFFFu);
            }
        }
    }
    __syncthreads();

    int rbase = (bkt << 6) + r0;
    for (int j = 0; j < 8; ++j) {
        int rr = (wid << 3) + j;          // 0..31 within my half
        int r = r0 + rr;
        int n = rbase + rr;
        if (n >= N) break;
        float acc0 = 0.f, acc1 = 0.f;
        if (fits) {
            int e0 = base[r] - myoff, e1 = e0 + cnt[r];
            int i = e0;
            for (; i + 8 <= e1; i += 8) {
                u64 p0 = sp[i],     p1 = sp[i + 1];
                u64 p2 = sp[i + 2], p3 = sp[i + 3];
                u64 p4 = sp[i + 4], p5 = sp[i + 5];
                u64 p6 = sp[i + 6], p7 = sp[i + 7];
                u32 c0 = RFL((u32)p0), b0 = RFL((u32)(p0 >> 32));
                u32 c1 = RFL((u32)p1), b1 = RFL((u32)(p1 >> 32));
                u32 c2 = RFL((u32)p2), b2 = RFL((u32)(p2 >> 32));
                u32 c3 = RFL((u32)p3), b3 = RFL((u32)(p3 >> 32));
                u32 c4 = RFL((u32)p4), b4 = RFL((u32)(p4 >> 32));
                u32 c5 = RFL((u32)p5), b5 = RFL((u32)(p5 >> 32));
                u32 c6 = RFL((u32)p6), b6 = RFL((u32)(p6 >> 32));
                u32 c7 = RFL((u32)p7), b7 = RFL((u32)(p7 >> 32));
                float g0 = bf2f(G[((size_t)c0 << 6) | lane]);
                float g1 = bf2f(G[((size_t)c1 << 6) | lane]);
                float g2 = bf2f(G[((size_t)c2 << 6) | lane]);
                float g3 = bf2f(G[((size_t)c3 << 6) | lane]);
                float g4 = bf2f(G[((size_t)c4 << 6) | lane]);
                float g5 = bf2f(G[((size_t)c5 << 6) | lane]);
                float g6 = bf2f(G[((size_t)c6 << 6) | lane]);
                float g7 = bf2f(G[((size_t)c7 << 6) | lane]);
                acc0 = fmaf(__uint_as_float(b0), g0, acc0);
                acc1 = fmaf(__uint_as_float(b1), g1, acc1);
                acc0 = fmaf(__uint_as_float(b2), g2, acc0);
                acc1 = fmaf(__uint_as_float(b3), g3, acc1);
                acc0 = fmaf(__uint_as_float(b4), g4, acc0);
                acc1 = fmaf(__uint_as_float(b5), g5, acc1);
                acc0 = fmaf(__uint_as_float(b6), g6, acc0);
                acc1 = fmaf(__uint_as_float(b7), g7, acc1);
            }
            for (; i < e1; ++i) {
                u64 p = sp[i];
                u32 c = RFL((u32)p), b = RFL((u32)(p >> 32));
                acc0 = fmaf(__uint_as_float(b), bf2f(G[((size_t)c << 6) | lane]), acc0);
            }
        } else {
            // overflow fallback (never expected): filter-scan the bucket
            for (int i = s; i < t; ++i) {
                u64 p = epair1[i];
                u32 mm = RFL((u32)p);
                if ((int)(mm >> 26) == r) {
                    u32 b = RFL((u32)(p >> 32));
                    acc0 = fmaf(__uint_as_float(b),
                                bf2f(G[((size_t)(mm & 0x03FFFFFFu) << 6) | lane]), acc0);
                }
            }
        }
        float o = acc0 + acc1 + bias[lane];

        float ssum = o;
#pragma unroll
        for (int off = 32; off; off >>= 1) ssum += __shfl_xor(ssum, off);
        float mu = ssum * 0.015625f;
        float dv = o - mu;
        float vs = dv * dv;
#pragma unroll
        for (int off = 32; off; off >>= 1) vs += __shfl_xor(vs, off);
        float inv = rsqrtf(vs * 0.015625f + 1e-5f);
        out[((size_t)n << 6) + lane] = dv * inv * gamma[lane] + beta[lane];
    }
}

extern "C" void kernel_launch(void* const* d_in, const int* in_sizes, int n_in,
                              void* d_out, int out_size, void* d_ws, size_t ws_size,
                              hipStream_t stream) {
    const float* feat  = (const float*)d_in[0];
    // d_in[1] = feat_ori: dead code in reference, unused
    const int*   row   = (const int*)d_in[2];
    const int*   col   = (const int*)d_in[3];
    const float* vals  = (const float*)d_in[4];
    const float* W     = (const float*)d_in[5];
    const float* bias  = (const float*)d_in[6];
    const float* gamma = (const float*)d_in[7];
    const float* beta  = (const float*)d_in[8];
    float* out = (float*)d_out;

    const int D = 64;
    int N = in_sizes[0] / D;   // 100000 -> NBK = 1563 <= MAXBK
    int E = in_sizes[2];

    int NBK  = (N + 63) / 64;
    int NBLK = NBLKC;
    int CH   = (((E + NBLK - 1) / NBLK) + 3) & ~3;   // edges/block, mult of 4
    int NG   = (N + 63) / 64;                        // gemm blocks

    // ws layout: G (bf16) | epair1 | hist2d (0.4MB) | btot | bbase
    char* ws = (char*)d_ws;
    u16*   G      = (u16*)ws;
    size_t off1   = (((size_t)N * 128) + 255) & ~(size_t)255;
    u64*   epair1 = (u64*)(ws + off1);
    size_t off2   = off1 + (((size_t)E * 8 + 255) & ~(size_t)255);
    u32*   hist2d = (u32*)(ws + off2);
    size_t off3   = off2 + (((size_t)NBLK * NBK * 4 + 255) & ~(size_t)255);
    u32*   btot   = (u32*)(ws + off3);
    u32*   bbase  = btot + NBK;          // NBK+1 entries

    k_bhist   <<<NBLK, 256, 0, stream>>>(row, hist2d, E, NBK, CH);
    k_bscan   <<<NBK, 256, 0, stream>>>(hist2d, btot, NBLK, NBK);
    k_scanb2  <<<1, 256, 0, stream>>>(btot, bbase, NBK, E);
    k_scatgemm<<<NBLK + NG, 256, 0, stream>>>(row, col, vals, hist2d, bbase,
                                              epair1, feat, W, G,
                                              E, N, NBK, NBLK, CH);
    k_node2   <<<NBK * 2, 256, 0, stream>>>(G, epair1, bbase, bias, gamma,
                                            beta, out, N);
}